// Round 5
// baseline (1068.700 us; speedup 1.0000x reference)
//
#include <hip/hip_runtime.h>
#include <hip/hip_fp16.h>

#define IN_F 256
#define OUT_F 256
#define RPB_SHIFT 9          // 512 rows per bin
#define NBINS_MAX 256        // ceil(100000/512)=196 <= 256

using bf16x8 = __attribute__((ext_vector_type(8))) short;
using f32x4  = __attribute__((ext_vector_type(4))) float;

__device__ inline short bf16rne(float f) {
    unsigned u = __float_as_uint(f);
    u = u + 0x7FFFu + ((u >> 16) & 1u);
    return (short)(u >> 16);
}
__device__ inline unsigned pack_half2(float a, float b) {
    __half2 h = __floats2half2_rn(a, b);
    return *reinterpret_cast<unsigned*>(&h);
}

// ---------------------------------------------------------------------------
// wt[n][k] = bf16(w[k][n])
// ---------------------------------------------------------------------------
__global__ __launch_bounds__(256) void convert_wt_kernel(
    const float* __restrict__ w, short* __restrict__ wt)
{
    const int idx = blockIdx.x * blockDim.x + threadIdx.x;
    const int c = idx >> 8, k = idx & 255;
    wt[(size_t)c * IN_F + k] = bf16rne(w[(size_t)k * OUT_F + c]);
}

// ---------------------------------------------------------------------------
// MFMA GEMM: sup16[M][256] = fp16( x @ W ), zero LDS.  (unchanged from R3)
// ---------------------------------------------------------------------------
__global__ __launch_bounds__(256) void mfma_gemm_kernel(
    const float* __restrict__ x, const short* __restrict__ wt,
    __half* __restrict__ sup16, int M)
{
    const int lane = threadIdx.x & 63;
    const int wid  = threadIdx.x >> 6;
    const int l15  = lane & 15;
    const int l4   = lane >> 4;
    const int rowbase = blockIdx.x * 64;
    const int cbase   = wid * 64;

    f32x4 acc[4][4];
#pragma unroll
    for (int rt = 0; rt < 4; ++rt)
#pragma unroll
        for (int ct = 0; ct < 4; ++ct)
            acc[rt][ct] = (f32x4){0.f, 0.f, 0.f, 0.f};

    const float* xp[4];
    const short* wp[4];
#pragma unroll
    for (int rt = 0; rt < 4; ++rt) {
        int r = rowbase + rt * 16 + l15;
        if (r > M - 1) r = M - 1;
        xp[rt] = x + (size_t)r * IN_F + l4 * 8;
    }
#pragma unroll
    for (int ct = 0; ct < 4; ++ct)
        wp[ct] = wt + (size_t)(cbase + ct * 16 + l15) * IN_F + l4 * 8;

#pragma unroll
    for (int k0 = 0; k0 < IN_F; k0 += 32) {
        bf16x8 b[4];
#pragma unroll
        for (int ct = 0; ct < 4; ++ct)
            b[ct] = *(const bf16x8*)(wp[ct] + k0);

        bf16x8 a[4];
#pragma unroll
        for (int rt = 0; rt < 4; ++rt) {
            const f32x4 f0 = __builtin_nontemporal_load((const f32x4*)(xp[rt] + k0));
            const f32x4 f1 = __builtin_nontemporal_load((const f32x4*)(xp[rt] + k0) + 1);
            bf16x8 v;
            v[0] = bf16rne(f0[0]); v[1] = bf16rne(f0[1]);
            v[2] = bf16rne(f0[2]); v[3] = bf16rne(f0[3]);
            v[4] = bf16rne(f1[0]); v[5] = bf16rne(f1[1]);
            v[6] = bf16rne(f1[2]); v[7] = bf16rne(f1[3]);
            a[rt] = v;
        }

#pragma unroll
        for (int rt = 0; rt < 4; ++rt)
#pragma unroll
            for (int ct = 0; ct < 4; ++ct)
                acc[rt][ct] = __builtin_amdgcn_mfma_f32_16x16x32_bf16(
                    b[ct], a[rt], acc[rt][ct], 0, 0, 0);
    }

#pragma unroll
    for (int rt = 0; rt < 4; ++rt) {
        const int r = rowbase + rt * 16 + l15;
        if (r >= M) continue;
#pragma unroll
        for (int ct = 0; ct < 4; ++ct) {
            uint2 pk;
            pk.x = pack_half2(acc[rt][ct][0], acc[rt][ct][1]);
            pk.y = pack_half2(acc[rt][ct][2], acc[rt][ct][3]);
            *(uint2*)(sup16 + (size_t)r * OUT_F + cbase + ct * 16 + l4 * 4) = pk;
        }
    }
}

// ---------------------------------------------------------------------------
// per-row edge counts
// ---------------------------------------------------------------------------
__global__ __launch_bounds__(256) void count_kernel(
    const int* __restrict__ ei, int* __restrict__ counts, int E)
{
    const int e = blockIdx.x * blockDim.x + threadIdx.x;
    if (e < E) atomicAdd(&counts[__builtin_nontemporal_load(ei + e)], 1);
}

// per-bin totals (100K atomics over <=196 addrs — negligible)
__global__ __launch_bounds__(256) void binsum_kernel(
    const int* __restrict__ counts, int* __restrict__ btot, int n)
{
    const int i = blockIdx.x * blockDim.x + threadIdx.x;
    if (i < n) atomicAdd(&btot[i >> RPB_SHIFT], counts[i]);
}

// exclusive scan of 256 bin totals -> three cursor copies
__global__ __launch_bounds__(NBINS_MAX) void scan_kernel(
    const int* __restrict__ btot, int* __restrict__ bstart,
    int* __restrict__ bclaim, int* __restrict__ bapp)
{
    __shared__ int t[NBINS_MAX];
    const int tid = threadIdx.x;
    const int v = btot[tid];
    t[tid] = v;
    __syncthreads();
    for (int d = 1; d < NBINS_MAX; d <<= 1) {
        const int u = (tid >= d) ? t[tid - d] : 0;
        __syncthreads();
        t[tid] += u;
        __syncthreads();
    }
    const int start = t[tid] - v;
    bstart[tid] = start; bclaim[tid] = start; bapp[tid] = start;
}

// rows claim contiguous segments INSIDE their bin region
__global__ __launch_bounds__(256) void claim_kernel(
    const int* __restrict__ counts, int* __restrict__ bclaim,
    int* __restrict__ cursor, int n)
{
    const int i = blockIdx.x * blockDim.x + threadIdx.x;
    if (i < n) cursor[i] = atomicAdd(&bclaim[i >> RPB_SHIFT], counts[i]);
}

// ---------------------------------------------------------------------------
// A1: coarse bin pass. Tile = 4096 edges, LDS hist -> intra-tile rank,
// one global reservation per active bin per tile. Entry = (w:32|col:17|rowLo:9).
// ---------------------------------------------------------------------------
__global__ __launch_bounds__(256) void a1_bin_kernel(
    const int* __restrict__ ei, const float* __restrict__ ew,
    int* __restrict__ bapp, unsigned long long* __restrict__ tscw, int E)
{
    __shared__ int hist[NBINS_MAX];
    __shared__ int rbase[NBINS_MAX];
    const int tid = threadIdx.x;
    hist[tid] = 0;
    __syncthreads();

    const int base = blockIdx.x * 4096;
    unsigned long long ent[16];
    int bins[16], rnk[16];

#pragma unroll
    for (int i = 0; i < 16; ++i) {
        const int e = base + i * 256 + tid;
        bins[i] = -1;
        if (e < E) {
            const int      row = __builtin_nontemporal_load(ei + e);
            const int      col = __builtin_nontemporal_load(ei + E + e);
            const unsigned wb  = __builtin_nontemporal_load((const unsigned*)ew + e);
            bins[i] = row >> RPB_SHIFT;
            rnk[i]  = atomicAdd(&hist[bins[i]], 1);
            ent[i]  = ((unsigned long long)wb << 32) |
                      ((unsigned)col << RPB_SHIFT) | (unsigned)(row & 511);
        }
    }
    __syncthreads();
    if (hist[tid] > 0) rbase[tid] = atomicAdd(&bapp[tid], hist[tid]);
    __syncthreads();

#pragma unroll
    for (int i = 0; i < 16; ++i)
        if (bins[i] >= 0)
            tscw[rbase[bins[i]] + rnk[i]] = ent[i];   // cached store: frontier fills in L2
}

// ---------------------------------------------------------------------------
// A2: scatter within bin (region ~130 KB -> L2-resident frontier).
// 4 blocks per bin. Advances cursor[row] from start to end.
// ---------------------------------------------------------------------------
__global__ __launch_bounds__(256) void a2_scatter_kernel(
    const unsigned long long* __restrict__ tscw, const int* __restrict__ bstart,
    const int* __restrict__ btot, int* __restrict__ cursor,
    unsigned long long* __restrict__ scw)
{
    const int bin = blockIdx.x >> 2, chunk = blockIdx.x & 3;
    const int n = btot[bin], s = bstart[bin];
    const int c0 = (n * chunk) >> 2, c1 = (n * (chunk + 1)) >> 2;
    for (int i = c0 + (int)threadIdx.x; i < c1; i += 256) {
        const unsigned long long en = __builtin_nontemporal_load(tscw + s + i);
        const int rowLo = (int)(en & 511u);
        const int col   = (int)((en >> RPB_SHIFT) & 0x1FFFFu);
        const int row   = (bin << RPB_SHIFT) | rowLo;
        const int pos   = atomicAdd(&cursor[row], 1);
        scw[pos] = (en & 0xFFFFFFFF00000000ull) | (unsigned)col;  // cached store
    }
}

// ---------------------------------------------------------------------------
// Pull (unchanged): one wave per row.
// ---------------------------------------------------------------------------
__global__ __launch_bounds__(256) void pull_kernel(
    const int* __restrict__ counts, const int* __restrict__ cursor,
    const unsigned long long* __restrict__ scw,
    const __half* __restrict__ sup16, const float* __restrict__ bias,
    float* __restrict__ out, int n)
{
    const int row = blockIdx.x * 4 + (threadIdx.x >> 6);
    if (row >= n) return;
    const int lane = threadIdx.x & 63;

    const int cnt   = counts[row];
    const int start = cursor[row] - cnt;

    float4 acc = *(const float4*)(bias + lane * 4);

#define GATHER_FMA(c, wt)                                                     \
    {                                                                         \
        const uint2 v = *(const uint2*)(sup16 + (size_t)(c) * OUT_F + lane * 4); \
        const float2 f0 = __half22float2(*(const __half2*)&v.x);              \
        const float2 f1 = __half22float2(*(const __half2*)&v.y);              \
        acc.x = fmaf((wt), f0.x, acc.x); acc.y = fmaf((wt), f0.y, acc.y);     \
        acc.z = fmaf((wt), f1.x, acc.z); acc.w = fmaf((wt), f1.y, acc.w);     \
    }

    for (int j0 = 0; j0 < cnt; j0 += 64) {
        unsigned long long pr = 0ull;
        if (j0 + lane < cnt)
            pr = __builtin_nontemporal_load(scw + start + j0 + lane);
        int   mycol = (int)(unsigned)pr;
        float myw   = __uint_as_float((unsigned)(pr >> 32));
        const int m = min(64, cnt - j0);

        int j = 0;
        for (; j + 4 <= m; j += 4) {
            const int   c0 = __shfl(mycol, j),     c1 = __shfl(mycol, j + 1);
            const int   c2 = __shfl(mycol, j + 2), c3 = __shfl(mycol, j + 3);
            const float w0 = __shfl(myw, j),       w1 = __shfl(myw, j + 1);
            const float w2 = __shfl(myw, j + 2),   w3 = __shfl(myw, j + 3);
            GATHER_FMA(c0, w0);
            GATHER_FMA(c1, w1);
            GATHER_FMA(c2, w2);
            GATHER_FMA(c3, w3);
        }
        for (; j < m; ++j) {
            const int   c  = __shfl(mycol, j);
            const float wj = __shfl(myw, j);
            GATHER_FMA(c, wj);
        }
    }
#undef GATHER_FMA

    f32x4 o; o[0] = acc.x; o[1] = acc.y; o[2] = acc.z; o[3] = acc.w;
    __builtin_nontemporal_store(o, (f32x4*)(out + (size_t)row * OUT_F + lane * 4));
}

// --------------------------- fallback path ---------------------------
__global__ __launch_bounds__(256) void bias_init_kernel(
    float* __restrict__ out, const float* __restrict__ bias, int total4)
{
    const float4* b4 = (const float4*)bias;
    float4* o4 = (float4*)out;
    for (int i = blockIdx.x * blockDim.x + threadIdx.x; i < total4;
         i += gridDim.x * blockDim.x)
        o4[i] = b4[i & 63];
}

__global__ __launch_bounds__(256) void edge_scatter_kernel(
    const int* __restrict__ ei, const float* __restrict__ ew,
    const __half* __restrict__ sup16, float* __restrict__ out, int E)
{
    const int e = blockIdx.x * 4 + (threadIdx.x >> 6);
    if (e >= E) return;
    const int lane = threadIdx.x & 63;
    const int   row = ei[e];
    const int   col = ei[E + e];
    const float wgt = ew[e];
    const uint2 v = *(const uint2*)(sup16 + (size_t)col * OUT_F + lane * 4);
    const float2 f0 = __half22float2(*(const __half2*)&v.x);
    const float2 f1 = __half22float2(*(const __half2*)&v.y);
    float* o = out + (size_t)row * OUT_F + lane * 4;
    unsafeAtomicAdd(o + 0, wgt * f0.x);
    unsafeAtomicAdd(o + 1, wgt * f0.y);
    unsafeAtomicAdd(o + 2, wgt * f1.x);
    unsafeAtomicAdd(o + 3, wgt * f1.y);
}

// ---------------------------------------------------------------------------
extern "C" void kernel_launch(void* const* d_in, const int* in_sizes, int n_in,
                              void* d_out, int out_size, void* d_ws, size_t ws_size,
                              hipStream_t stream)
{
    const float* x    = (const float*)d_in[0];
    const int*   ei   = (const int*)d_in[1];
    const float* ew   = (const float*)d_in[2];
    const float* w    = (const float*)d_in[3];
    const float* bias = (const float*)d_in[4];
    float* out = (float*)d_out;

    const int M = in_sizes[0] / IN_F;   // 100000
    const int E = in_sizes[2];          // 3,200,000
    const int nbins = (M + (1 << RPB_SHIFT) - 1) >> RPB_SHIFT;  // 196

    // workspace: sup16 | counts | btot | cursor | bstart | bclaim | bapp | scw | tscw | wt
    char* p = (char*)d_ws;
    const size_t sup_b    = (((size_t)M * OUT_F * sizeof(__half)) + 255) & ~255ull;
    const size_t counts_b = ((size_t)M * 4 + 255) & ~255ull;
    const size_t btot_b   = NBINS_MAX * 4;                       // 1 KB
    const size_t cursor_b = counts_b;
    const size_t barr_b   = NBINS_MAX * 4;
    const size_t scw_b    = ((size_t)E * 8 + 255) & ~255ull;
    const size_t tscw_b   = scw_b;
    const size_t wt_b     = (size_t)IN_F * OUT_F * sizeof(short);
    const size_t need     = sup_b + counts_b + btot_b + cursor_b + 3 * barr_b
                          + scw_b + tscw_b + wt_b;

    __half* sup16  = (__half*)p;               p += sup_b;
    int*    counts = (int*)p;                  p += counts_b;
    int*    btot   = (int*)p;                  p += btot_b;
    int*    cursor = (int*)p;                  p += cursor_b;
    int*    bstart = (int*)p;                  p += barr_b;
    int*    bclaim = (int*)p;                  p += barr_b;
    int*    bapp   = (int*)p;                  p += barr_b;
    unsigned long long* scw  = (unsigned long long*)p;  p += scw_b;
    unsigned long long* tscw = (unsigned long long*)p;  p += tscw_b;
    short*  wtb    = (short*)p;

    // 1) wt = bf16(w^T); sup16 = fp16(x @ W) via MFMA
    convert_wt_kernel<<<(IN_F * OUT_F) / 256, 256, 0, stream>>>(w, wtb);
    mfma_gemm_kernel<<<(M + 63) / 64, 256, 0, stream>>>(x, wtb, sup16, M);

    if (ws_size >= need) {
        hipMemsetAsync(counts, 0, counts_b + btot_b, stream);   // counts + btot
        count_kernel<<<(E + 255) / 256, 256, 0, stream>>>(ei, counts, E);
        binsum_kernel<<<(M + 255) / 256, 256, 0, stream>>>(counts, btot, M);
        scan_kernel<<<1, NBINS_MAX, 0, stream>>>(btot, bstart, bclaim, bapp);
        claim_kernel<<<(M + 255) / 256, 256, 0, stream>>>(counts, bclaim, cursor, M);
        a1_bin_kernel<<<(E + 4095) / 4096, 256, 0, stream>>>(ei, ew, bapp, tscw, E);
        a2_scatter_kernel<<<nbins * 4, 256, 0, stream>>>(tscw, bstart, btot, cursor, scw);
        pull_kernel<<<(M + 3) / 4, 256, 0, stream>>>(
            counts, cursor, scw, sup16, bias, out, M);
    } else {
        const int total4 = M * OUT_F / 4;
        bias_init_kernel<<<2048, 256, 0, stream>>>(out, bias, total4);
        edge_scatter_kernel<<<(E + 3) / 4, 256, 0, stream>>>(ei, ew, sup16, out, E);
    }
}

// Round 6
// 624.173 us; speedup vs baseline: 1.7122x; 1.7122x over previous
//
#include <hip/hip_runtime.h>
#include <hip/hip_fp16.h>

#define IN_F 256
#define OUT_F 256
#define RPB_SHIFT 9          // 512 rows per bin
#define RPB (1 << RPB_SHIFT)
#define NBINS_MAX 256        // ceil(100000/512)=196 <= 256
#define TILE_E 4096          // edges per a1 tile

using bf16x8 = __attribute__((ext_vector_type(8))) short;
using f32x4  = __attribute__((ext_vector_type(4))) float;

__device__ inline short bf16rne(float f) {
    unsigned u = __float_as_uint(f);
    u = u + 0x7FFFu + ((u >> 16) & 1u);
    return (short)(u >> 16);
}
__device__ inline unsigned pack_half2(float a, float b) {
    __half2 h = __floats2half2_rn(a, b);
    return *reinterpret_cast<unsigned*>(&h);
}

// ---------------------------------------------------------------------------
// wt[n][k] = bf16(w[k][n])
// ---------------------------------------------------------------------------
__global__ __launch_bounds__(256) void convert_wt_kernel(
    const float* __restrict__ w, short* __restrict__ wt)
{
    const int idx = blockIdx.x * blockDim.x + threadIdx.x;
    const int c = idx >> 8, k = idx & 255;
    wt[(size_t)c * IN_F + k] = bf16rne(w[(size_t)k * OUT_F + c]);
}

// ---------------------------------------------------------------------------
// MFMA GEMM: sup16[M][256] = fp16( x @ W ), zero LDS.  (unchanged)
// ---------------------------------------------------------------------------
__global__ __launch_bounds__(256) void mfma_gemm_kernel(
    const float* __restrict__ x, const short* __restrict__ wt,
    __half* __restrict__ sup16, int M)
{
    const int lane = threadIdx.x & 63;
    const int wid  = threadIdx.x >> 6;
    const int l15  = lane & 15;
    const int l4   = lane >> 4;
    const int rowbase = blockIdx.x * 64;
    const int cbase   = wid * 64;

    f32x4 acc[4][4];
#pragma unroll
    for (int rt = 0; rt < 4; ++rt)
#pragma unroll
        for (int ct = 0; ct < 4; ++ct)
            acc[rt][ct] = (f32x4){0.f, 0.f, 0.f, 0.f};

    const float* xp[4];
    const short* wp[4];
#pragma unroll
    for (int rt = 0; rt < 4; ++rt) {
        int r = rowbase + rt * 16 + l15;
        if (r > M - 1) r = M - 1;
        xp[rt] = x + (size_t)r * IN_F + l4 * 8;
    }
#pragma unroll
    for (int ct = 0; ct < 4; ++ct)
        wp[ct] = wt + (size_t)(cbase + ct * 16 + l15) * IN_F + l4 * 8;

#pragma unroll
    for (int k0 = 0; k0 < IN_F; k0 += 32) {
        bf16x8 b[4];
#pragma unroll
        for (int ct = 0; ct < 4; ++ct)
            b[ct] = *(const bf16x8*)(wp[ct] + k0);

        bf16x8 a[4];
#pragma unroll
        for (int rt = 0; rt < 4; ++rt) {
            const f32x4 f0 = __builtin_nontemporal_load((const f32x4*)(xp[rt] + k0));
            const f32x4 f1 = __builtin_nontemporal_load((const f32x4*)(xp[rt] + k0) + 1);
            bf16x8 v;
            v[0] = bf16rne(f0[0]); v[1] = bf16rne(f0[1]);
            v[2] = bf16rne(f0[2]); v[3] = bf16rne(f0[3]);
            v[4] = bf16rne(f1[0]); v[5] = bf16rne(f1[1]);
            v[6] = bf16rne(f1[2]); v[7] = bf16rne(f1[3]);
            a[rt] = v;
        }

#pragma unroll
        for (int rt = 0; rt < 4; ++rt)
#pragma unroll
            for (int ct = 0; ct < 4; ++ct)
                acc[rt][ct] = __builtin_amdgcn_mfma_f32_16x16x32_bf16(
                    b[ct], a[rt], acc[rt][ct], 0, 0, 0);
    }

#pragma unroll
    for (int rt = 0; rt < 4; ++rt) {
        const int r = rowbase + rt * 16 + l15;
        if (r >= M) continue;
#pragma unroll
        for (int ct = 0; ct < 4; ++ct) {
            uint2 pk;
            pk.x = pack_half2(acc[rt][ct][0], acc[rt][ct][1]);
            pk.y = pack_half2(acc[rt][ct][2], acc[rt][ct][3]);
            *(uint2*)(sup16 + (size_t)r * OUT_F + cbase + ct * 16 + l4 * 4) = pk;
        }
    }
}

// ---------------------------------------------------------------------------
// per-row edge counts (non-returning atomics over 100K addrs — measured cheap)
// ---------------------------------------------------------------------------
__global__ __launch_bounds__(256) void count_kernel(
    const int* __restrict__ ei, int* __restrict__ counts, int E)
{
    const int e = blockIdx.x * blockDim.x + threadIdx.x;
    if (e < E) atomicAdd(&counts[__builtin_nontemporal_load(ei + e)], 1);
}

// ---------------------------------------------------------------------------
// btot[bin] = sum of its 512 counts  (block reduce, NO atomics)
// ---------------------------------------------------------------------------
__global__ __launch_bounds__(256) void bin_total_kernel(
    const int* __restrict__ counts, int* __restrict__ btot, int M)
{
    const int bin  = blockIdx.x;
    const int base = bin << RPB_SHIFT;
    const int tid  = threadIdx.x;
    int v = 0;
#pragma unroll
    for (int i = 0; i < RPB / 256; ++i) {
        const int r = base + tid + i * 256;
        if (r < M) v += counts[r];
    }
    __shared__ int s[256];
    s[tid] = v; __syncthreads();
    for (int d = 128; d > 0; d >>= 1) {
        if (tid < d) s[tid] += s[tid + d];
        __syncthreads();
    }
    if (tid == 0) btot[bin] = s[0];
}

// exclusive scan of bin totals (1 block, NO atomics)
__global__ __launch_bounds__(NBINS_MAX) void bin_scan_kernel(
    const int* __restrict__ btot, int* __restrict__ bstart, int nbins)
{
    __shared__ int s[NBINS_MAX];
    const int tid = threadIdx.x;
    const int v = (tid < nbins) ? btot[tid] : 0;
    s[tid] = v;
    __syncthreads();
    for (int d = 1; d < NBINS_MAX; d <<= 1) {
        const int u = (tid >= d) ? s[tid - d] : 0;
        __syncthreads();
        s[tid] += u;
        __syncthreads();
    }
    bstart[tid] = s[tid] - v;
}

// cursor[row] = bstart[bin] + exclusive scan of counts within bin (NO atomics)
__global__ __launch_bounds__(256) void row_scan_kernel(
    const int* __restrict__ counts, const int* __restrict__ bstart,
    int* __restrict__ cursor, int M)
{
    const int bin  = blockIdx.x;
    const int base = bin << RPB_SHIFT;
    const int tid  = threadIdx.x;
    const int r0 = base + 2 * tid, r1 = r0 + 1;
    const int c0 = (r0 < M) ? counts[r0] : 0;
    const int c1 = (r1 < M) ? counts[r1] : 0;
    __shared__ int s[256];
    const int own = c0 + c1;
    s[tid] = own;
    __syncthreads();
    for (int d = 1; d < 256; d <<= 1) {
        const int u = (tid >= d) ? s[tid - d] : 0;
        __syncthreads();
        s[tid] += u;
        __syncthreads();
    }
    const int excl = s[tid] - own + bstart[bin];
    if (r0 < M) cursor[r0] = excl;
    if (r1 < M) cursor[r1] = excl + c0;
}

// ---------------------------------------------------------------------------
// a1a: per-tile bin histogram -> thist[t][b]   (LDS atomics only)
// ---------------------------------------------------------------------------
__global__ __launch_bounds__(256) void a1a_hist_kernel(
    const int* __restrict__ ei, int* __restrict__ thist, int E)
{
    __shared__ int hist[NBINS_MAX];
    const int tid = threadIdx.x;
    hist[tid] = 0;
    __syncthreads();
    const int base = blockIdx.x * TILE_E;
#pragma unroll
    for (int i = 0; i < TILE_E / 256; ++i) {
        const int e = base + i * 256 + tid;
        if (e < E)
            atomicAdd(&hist[__builtin_nontemporal_load(ei + e) >> RPB_SHIFT], 1);
    }
    __syncthreads();
    thist[(size_t)blockIdx.x * NBINS_MAX + tid] = hist[tid];
}

// per-bin exclusive scan over tiles, in place (196 blocks, NO global atomics)
__global__ __launch_bounds__(256) void tile_scan_kernel(
    int* __restrict__ thist, int T)
{
    const int b   = blockIdx.x;
    const int tid = threadIdx.x;
    __shared__ int s[256];
    int carry = 0;
    for (int c0 = 0; c0 < T; c0 += 256) {
        const int t = c0 + tid;
        const int v = (t < T) ? thist[(size_t)t * NBINS_MAX + b] : 0;
        s[tid] = v;
        __syncthreads();
        for (int d = 1; d < 256; d <<= 1) {
            const int u = (tid >= d) ? s[tid - d] : 0;
            __syncthreads();
            s[tid] += u;
            __syncthreads();
        }
        const int total = s[255];
        if (t < T) thist[(size_t)t * NBINS_MAX + b] = carry + s[tid] - v;
        carry += total;
        __syncthreads();
    }
}

// ---------------------------------------------------------------------------
// a1b: deterministic binned scatter. pos = bstart[b] + thist[t][b] + LDS-rank.
// Entry = (w:32 | col:17 | rowLo:9)
// ---------------------------------------------------------------------------
__global__ __launch_bounds__(256) void a1b_scatter_kernel(
    const int* __restrict__ ei, const float* __restrict__ ew,
    const int* __restrict__ bstart, const int* __restrict__ thist,
    unsigned long long* __restrict__ tscw, int E)
{
    __shared__ int hist[NBINS_MAX];
    __shared__ int rbase[NBINS_MAX];
    const int tid = threadIdx.x;
    hist[tid]  = 0;
    rbase[tid] = bstart[tid] + thist[(size_t)blockIdx.x * NBINS_MAX + tid];
    __syncthreads();
    const int base = blockIdx.x * TILE_E;
#pragma unroll
    for (int i = 0; i < TILE_E / 256; ++i) {
        const int e = base + i * 256 + tid;
        if (e < E) {
            const int      row = __builtin_nontemporal_load(ei + e);
            const int      col = __builtin_nontemporal_load(ei + E + e);
            const unsigned wb  = __builtin_nontemporal_load((const unsigned*)ew + e);
            const int b   = row >> RPB_SHIFT;
            const int rnk = atomicAdd(&hist[b], 1);
            tscw[rbase[b] + rnk] = ((unsigned long long)wb << 32) |
                                   ((unsigned)col << RPB_SHIFT) |
                                   (unsigned)(row & (RPB - 1));
        }
    }
}

// ---------------------------------------------------------------------------
// a2: one persistent block per bin -> scatter frontier is one XCD-local
// ~130 KB region; cursor atomics contend ~32-way only.
// ---------------------------------------------------------------------------
__global__ __launch_bounds__(256) void a2_scatter_kernel(
    const unsigned long long* __restrict__ tscw, const int* __restrict__ bstart,
    const int* __restrict__ btot, int* __restrict__ cursor,
    unsigned long long* __restrict__ scw)
{
    const int b  = blockIdx.x;
    const int n  = btot[b];
    const int s0 = bstart[b];
    for (int i = threadIdx.x; i < n; i += 256) {
        const unsigned long long en = __builtin_nontemporal_load(tscw + s0 + i);
        const int row = (b << RPB_SHIFT) | (int)(en & (RPB - 1));
        const int pos = atomicAdd(&cursor[row], 1);
        scw[pos] = (en & 0xFFFFFFFF00000000ull) |
                   (unsigned)((en >> RPB_SHIFT) & 0x1FFFFu);
    }
}

// ---------------------------------------------------------------------------
// Pull (unchanged): one wave per row.
// ---------------------------------------------------------------------------
__global__ __launch_bounds__(256) void pull_kernel(
    const int* __restrict__ counts, const int* __restrict__ cursor,
    const unsigned long long* __restrict__ scw,
    const __half* __restrict__ sup16, const float* __restrict__ bias,
    float* __restrict__ out, int n)
{
    const int row = blockIdx.x * 4 + (threadIdx.x >> 6);
    if (row >= n) return;
    const int lane = threadIdx.x & 63;

    const int cnt   = counts[row];
    const int start = cursor[row] - cnt;

    float4 acc = *(const float4*)(bias + lane * 4);

#define GATHER_FMA(c, wt)                                                     \
    {                                                                         \
        const uint2 v = *(const uint2*)(sup16 + (size_t)(c) * OUT_F + lane * 4); \
        const float2 f0 = __half22float2(*(const __half2*)&v.x);              \
        const float2 f1 = __half22float2(*(const __half2*)&v.y);              \
        acc.x = fmaf((wt), f0.x, acc.x); acc.y = fmaf((wt), f0.y, acc.y);     \
        acc.z = fmaf((wt), f1.x, acc.z); acc.w = fmaf((wt), f1.y, acc.w);     \
    }

    for (int j0 = 0; j0 < cnt; j0 += 64) {
        unsigned long long pr = 0ull;
        if (j0 + lane < cnt)
            pr = __builtin_nontemporal_load(scw + start + j0 + lane);
        int   mycol = (int)(unsigned)pr;
        float myw   = __uint_as_float((unsigned)(pr >> 32));
        const int m = min(64, cnt - j0);

        int j = 0;
        for (; j + 4 <= m; j += 4) {
            const int   c0 = __shfl(mycol, j),     c1 = __shfl(mycol, j + 1);
            const int   c2 = __shfl(mycol, j + 2), c3 = __shfl(mycol, j + 3);
            const float w0 = __shfl(myw, j),       w1 = __shfl(myw, j + 1);
            const float w2 = __shfl(myw, j + 2),   w3 = __shfl(myw, j + 3);
            GATHER_FMA(c0, w0);
            GATHER_FMA(c1, w1);
            GATHER_FMA(c2, w2);
            GATHER_FMA(c3, w3);
        }
        for (; j < m; ++j) {
            const int   c  = __shfl(mycol, j);
            const float wj = __shfl(myw, j);
            GATHER_FMA(c, wj);
        }
    }
#undef GATHER_FMA

    f32x4 o; o[0] = acc.x; o[1] = acc.y; o[2] = acc.z; o[3] = acc.w;
    __builtin_nontemporal_store(o, (f32x4*)(out + (size_t)row * OUT_F + lane * 4));
}

// --------------------------- fallback path ---------------------------
__global__ __launch_bounds__(256) void bias_init_kernel(
    float* __restrict__ out, const float* __restrict__ bias, int total4)
{
    const float4* b4 = (const float4*)bias;
    float4* o4 = (float4*)out;
    for (int i = blockIdx.x * blockDim.x + threadIdx.x; i < total4;
         i += gridDim.x * blockDim.x)
        o4[i] = b4[i & 63];
}

__global__ __launch_bounds__(256) void edge_scatter_kernel(
    const int* __restrict__ ei, const float* __restrict__ ew,
    const __half* __restrict__ sup16, float* __restrict__ out, int E)
{
    const int e = blockIdx.x * 4 + (threadIdx.x >> 6);
    if (e >= E) return;
    const int lane = threadIdx.x & 63;
    const int   row = ei[e];
    const int   col = ei[E + e];
    const float wgt = ew[e];
    const uint2 v = *(const uint2*)(sup16 + (size_t)col * OUT_F + lane * 4);
    const float2 f0 = __half22float2(*(const __half2*)&v.x);
    const float2 f1 = __half22float2(*(const __half2*)&v.y);
    float* o = out + (size_t)row * OUT_F + lane * 4;
    unsafeAtomicAdd(o + 0, wgt * f0.x);
    unsafeAtomicAdd(o + 1, wgt * f0.y);
    unsafeAtomicAdd(o + 2, wgt * f1.x);
    unsafeAtomicAdd(o + 3, wgt * f1.y);
}

// ---------------------------------------------------------------------------
extern "C" void kernel_launch(void* const* d_in, const int* in_sizes, int n_in,
                              void* d_out, int out_size, void* d_ws, size_t ws_size,
                              hipStream_t stream)
{
    const float* x    = (const float*)d_in[0];
    const int*   ei   = (const int*)d_in[1];
    const float* ew   = (const float*)d_in[2];
    const float* w    = (const float*)d_in[3];
    const float* bias = (const float*)d_in[4];
    float* out = (float*)d_out;

    const int M = in_sizes[0] / IN_F;   // 100000
    const int E = in_sizes[2];          // 3,200,000
    const int nbins = (M + RPB - 1) >> RPB_SHIFT;        // 196
    const int T     = (E + TILE_E - 1) / TILE_E;         // 782

    // workspace: sup16 | counts | btot | cursor | bstart | thist | scw | tscw | wt
    char* p = (char*)d_ws;
    const size_t sup_b    = (((size_t)M * OUT_F * sizeof(__half)) + 255) & ~255ull;
    const size_t counts_b = ((size_t)M * 4 + 255) & ~255ull;
    const size_t btot_b   = NBINS_MAX * 4;
    const size_t cursor_b = counts_b;
    const size_t bstart_b = NBINS_MAX * 4;
    const size_t thist_b  = (((size_t)T * NBINS_MAX * 4) + 255) & ~255ull;  // ~800 KB
    const size_t scw_b    = ((size_t)E * 8 + 255) & ~255ull;
    const size_t tscw_b   = scw_b;
    const size_t wt_b     = (size_t)IN_F * OUT_F * sizeof(short);
    const size_t need     = sup_b + counts_b + btot_b + cursor_b + bstart_b
                          + thist_b + scw_b + tscw_b + wt_b;

    __half* sup16  = (__half*)p;               p += sup_b;
    int*    counts = (int*)p;                  p += counts_b;
    int*    btot   = (int*)p;                  p += btot_b;
    int*    cursor = (int*)p;                  p += cursor_b;
    int*    bstart = (int*)p;                  p += bstart_b;
    int*    thist  = (int*)p;                  p += thist_b;
    unsigned long long* scw  = (unsigned long long*)p;  p += scw_b;
    unsigned long long* tscw = (unsigned long long*)p;  p += tscw_b;
    short*  wtb    = (short*)p;

    // 1) wt = bf16(w^T); sup16 = fp16(x @ W) via MFMA
    convert_wt_kernel<<<(IN_F * OUT_F) / 256, 256, 0, stream>>>(w, wtb);
    mfma_gemm_kernel<<<(M + 63) / 64, 256, 0, stream>>>(x, wtb, sup16, M);

    if (ws_size >= need) {
        hipMemsetAsync(counts, 0, (size_t)M * 4, stream);
        count_kernel<<<(E + 255) / 256, 256, 0, stream>>>(ei, counts, E);
        bin_total_kernel<<<nbins, 256, 0, stream>>>(counts, btot, M);
        bin_scan_kernel<<<1, NBINS_MAX, 0, stream>>>(btot, bstart, nbins);
        row_scan_kernel<<<nbins, 256, 0, stream>>>(counts, bstart, cursor, M);
        a1a_hist_kernel<<<T, 256, 0, stream>>>(ei, thist, E);
        tile_scan_kernel<<<nbins, 256, 0, stream>>>(thist, T);
        a1b_scatter_kernel<<<T, 256, 0, stream>>>(ei, ew, bstart, thist, tscw, E);
        a2_scatter_kernel<<<nbins, 256, 0, stream>>>(tscw, bstart, btot, cursor, scw);
        pull_kernel<<<(M + 3) / 4, 256, 0, stream>>>(
            counts, cursor, scw, sup16, bias, out, M);
    } else {
        const int total4 = M * OUT_F / 4;
        bias_init_kernel<<<2048, 256, 0, stream>>>(out, bias, total4);
        edge_scatter_kernel<<<(E + 3) / 4, 256, 0, stream>>>(ei, ew, sup16, out, E);
    }
}

// Round 7
// 471.450 us; speedup vs baseline: 2.2668x; 1.3239x over previous
//
#include <hip/hip_runtime.h>
#include <hip/hip_fp16.h>

#define IN_F 256
#define OUT_F 256
#define HALF_F 128
#define RPB_SHIFT 9          // 512 rows per bin
#define RPB (1 << RPB_SHIFT)
#define NBINS_MAX 256
#define TILE_E 4096

using bf16x8 = __attribute__((ext_vector_type(8))) short;
using f32x4  = __attribute__((ext_vector_type(4))) float;
using ull    = unsigned long long;

__device__ inline short bf16rne(float f) {
    unsigned u = __float_as_uint(f);
    u = u + 0x7FFFu + ((u >> 16) & 1u);
    return (short)(u >> 16);
}
__device__ inline unsigned pack_half2(float a, float b) {
    __half2 h = __floats2half2_rn(a, b);
    return *reinterpret_cast<unsigned*>(&h);
}

// ---------------------------------------------------------------------------
// wt[n][k] = bf16(w[k][n])
// ---------------------------------------------------------------------------
__global__ __launch_bounds__(256) void convert_wt_kernel(
    const float* __restrict__ w, short* __restrict__ wt)
{
    const int idx = blockIdx.x * blockDim.x + threadIdx.x;
    const int c = idx >> 8, k = idx & 255;
    wt[(size_t)c * IN_F + k] = bf16rne(w[(size_t)k * OUT_F + c]);
}

// ---------------------------------------------------------------------------
// MFMA GEMM -> split fp16 buffers supA (features 0..127), supB (128..255)
// ---------------------------------------------------------------------------
__global__ __launch_bounds__(256) void mfma_gemm_kernel(
    const float* __restrict__ x, const short* __restrict__ wt,
    __half* __restrict__ supA, __half* __restrict__ supB, int M)
{
    const int lane = threadIdx.x & 63;
    const int wid  = threadIdx.x >> 6;
    const int l15  = lane & 15;
    const int l4   = lane >> 4;
    const int rowbase = blockIdx.x * 64;
    const int cbase   = wid * 64;

    f32x4 acc[4][4];
#pragma unroll
    for (int rt = 0; rt < 4; ++rt)
#pragma unroll
        for (int ct = 0; ct < 4; ++ct)
            acc[rt][ct] = (f32x4){0.f, 0.f, 0.f, 0.f};

    const float* xp[4];
    const short* wp[4];
#pragma unroll
    for (int rt = 0; rt < 4; ++rt) {
        int r = rowbase + rt * 16 + l15;
        if (r > M - 1) r = M - 1;
        xp[rt] = x + (size_t)r * IN_F + l4 * 8;
    }
#pragma unroll
    for (int ct = 0; ct < 4; ++ct)
        wp[ct] = wt + (size_t)(cbase + ct * 16 + l15) * IN_F + l4 * 8;

#pragma unroll
    for (int k0 = 0; k0 < IN_F; k0 += 32) {
        bf16x8 b[4];
#pragma unroll
        for (int ct = 0; ct < 4; ++ct)
            b[ct] = *(const bf16x8*)(wp[ct] + k0);

        bf16x8 a[4];
#pragma unroll
        for (int rt = 0; rt < 4; ++rt) {
            const f32x4 f0 = __builtin_nontemporal_load((const f32x4*)(xp[rt] + k0));
            const f32x4 f1 = __builtin_nontemporal_load((const f32x4*)(xp[rt] + k0) + 1);
            bf16x8 v;
            v[0] = bf16rne(f0[0]); v[1] = bf16rne(f0[1]);
            v[2] = bf16rne(f0[2]); v[3] = bf16rne(f0[3]);
            v[4] = bf16rne(f1[0]); v[5] = bf16rne(f1[1]);
            v[6] = bf16rne(f1[2]); v[7] = bf16rne(f1[3]);
            a[rt] = v;
        }

#pragma unroll
        for (int rt = 0; rt < 4; ++rt)
#pragma unroll
            for (int ct = 0; ct < 4; ++ct)
                acc[rt][ct] = __builtin_amdgcn_mfma_f32_16x16x32_bf16(
                    b[ct], a[rt], acc[rt][ct], 0, 0, 0);
    }

    __half* dst = (wid < 2) ? supA : supB;
    const int fbase = (wid & 1) * 64;
#pragma unroll
    for (int rt = 0; rt < 4; ++rt) {
        const int r = rowbase + rt * 16 + l15;
        if (r >= M) continue;
#pragma unroll
        for (int ct = 0; ct < 4; ++ct) {
            uint2 pk;
            pk.x = pack_half2(acc[rt][ct][0], acc[rt][ct][1]);
            pk.y = pack_half2(acc[rt][ct][2], acc[rt][ct][3]);
            *(uint2*)(dst + (size_t)r * HALF_F + fbase + ct * 16 + l4 * 4) = pk;
        }
    }
}

// ---------------------------------------------------------------------------
// a1a: per-tile bin histogram -> thist[t][b]   (LDS atomics only)
// ---------------------------------------------------------------------------
__global__ __launch_bounds__(256) void a1a_hist_kernel(
    const int* __restrict__ ei, int* __restrict__ thist, int E)
{
    __shared__ int hist[NBINS_MAX];
    const int tid = threadIdx.x;
    hist[tid] = 0;
    __syncthreads();
    const int base = blockIdx.x * TILE_E;
#pragma unroll
    for (int i = 0; i < TILE_E / 256; ++i) {
        const int e = base + i * 256 + tid;
        if (e < E)
            atomicAdd(&hist[__builtin_nontemporal_load(ei + e) >> RPB_SHIFT], 1);
    }
    __syncthreads();
    thist[(size_t)blockIdx.x * NBINS_MAX + tid] = hist[tid];
}

// per-bin exclusive scan over tiles, in place; also emits btot[b]
__global__ __launch_bounds__(256) void tile_scan_kernel(
    int* __restrict__ thist, int* __restrict__ btot, int T)
{
    const int b   = blockIdx.x;
    const int tid = threadIdx.x;
    __shared__ int s[256];
    int carry = 0;
    for (int c0 = 0; c0 < T; c0 += 256) {
        const int t = c0 + tid;
        const int v = (t < T) ? thist[(size_t)t * NBINS_MAX + b] : 0;
        s[tid] = v;
        __syncthreads();
        for (int d = 1; d < 256; d <<= 1) {
            const int u = (tid >= d) ? s[tid - d] : 0;
            __syncthreads();
            s[tid] += u;
            __syncthreads();
        }
        const int total = s[255];
        if (t < T) thist[(size_t)t * NBINS_MAX + b] = carry + s[tid] - v;
        carry += total;
        __syncthreads();
    }
    if (tid == 0) btot[b] = carry;
}

// exclusive scan of bin totals (1 block)
__global__ __launch_bounds__(NBINS_MAX) void bin_scan_kernel(
    const int* __restrict__ btot, int* __restrict__ bstart, int nbins)
{
    __shared__ int s[NBINS_MAX];
    const int tid = threadIdx.x;
    const int v = (tid < nbins) ? btot[tid] : 0;
    s[tid] = v;
    __syncthreads();
    for (int d = 1; d < NBINS_MAX; d <<= 1) {
        const int u = (tid >= d) ? s[tid - d] : 0;
        __syncthreads();
        s[tid] += u;
        __syncthreads();
    }
    bstart[tid] = s[tid] - v;
}

// ---------------------------------------------------------------------------
// a1b: deterministic binned scatter. pos = bstart[b] + thist[t][b] + LDS-rank.
// Entry = (w:32 | col:17 | rowLo:9)
// ---------------------------------------------------------------------------
__global__ __launch_bounds__(256) void a1b_scatter_kernel(
    const int* __restrict__ ei, const float* __restrict__ ew,
    const int* __restrict__ bstart, const int* __restrict__ thist,
    ull* __restrict__ tscw, int E)
{
    __shared__ int hist[NBINS_MAX];
    __shared__ int rbase[NBINS_MAX];
    const int tid = threadIdx.x;
    hist[tid]  = 0;
    rbase[tid] = bstart[tid] + thist[(size_t)blockIdx.x * NBINS_MAX + tid];
    __syncthreads();
    const int base = blockIdx.x * TILE_E;
#pragma unroll
    for (int i = 0; i < TILE_E / 256; ++i) {
        const int e = base + i * 256 + tid;
        if (e < E) {
            const int      row = __builtin_nontemporal_load(ei + e);
            const int      col = __builtin_nontemporal_load(ei + E + e);
            const unsigned wb  = __builtin_nontemporal_load((const unsigned*)ew + e);
            const int b   = row >> RPB_SHIFT;
            const int rnk = atomicAdd(&hist[b], 1);
            tscw[rbase[b] + rnk] = ((ull)wb << 32) |
                                   ((unsigned)col << RPB_SHIFT) |
                                   (unsigned)(row & (RPB - 1));
        }
    }
}

// ---------------------------------------------------------------------------
// a2: in-bin LDS counting sort. One block per bin. Emits row-sorted scw,
// plus counts[row] and cursor[row] (= segment start). No global atomics.
// ---------------------------------------------------------------------------
__global__ __launch_bounds__(256) void a2_sort_kernel(
    const ull* __restrict__ tscw, const int* __restrict__ bstart,
    const int* __restrict__ btot, int* __restrict__ counts,
    int* __restrict__ cursor, ull* __restrict__ scw, int M)
{
    const int b   = blockIdx.x;
    const int tid = threadIdx.x;
    const int n   = btot[b];
    const int s0  = bstart[b];

    __shared__ int hist[RPB];
    __shared__ int cur[RPB];
    __shared__ int s[256];

    hist[tid] = 0; hist[tid + 256] = 0;
    __syncthreads();

    for (int i = tid; i < n; i += 256)
        atomicAdd(&hist[(int)(__builtin_nontemporal_load(tscw + s0 + i) & (RPB - 1))], 1);
    __syncthreads();

    // exclusive scan of 512 via 256 threads (2 elems each)
    const int h0 = hist[2 * tid], h1 = hist[2 * tid + 1];
    const int own = h0 + h1;
    s[tid] = own;
    __syncthreads();
    for (int d = 1; d < 256; d <<= 1) {
        const int u = (tid >= d) ? s[tid - d] : 0;
        __syncthreads();
        s[tid] += u;
        __syncthreads();
    }
    const int excl = s[tid] - own;

    const int r0 = (b << RPB_SHIFT) + 2 * tid, r1 = r0 + 1;
    cur[2 * tid]     = s0 + excl;
    cur[2 * tid + 1] = s0 + excl + h0;
    if (r0 < M) { counts[r0] = h0; cursor[r0] = s0 + excl; }
    if (r1 < M) { counts[r1] = h1; cursor[r1] = s0 + excl + h0; }
    __syncthreads();

    for (int i = tid; i < n; i += 256) {
        const ull en = __builtin_nontemporal_load(tscw + s0 + i);
        const int pos = atomicAdd(&cur[(int)(en & (RPB - 1))], 1);
        scw[pos] = (en & 0xFFFFFFFF00000000ull) |
                   (unsigned)((en >> RPB_SHIFT) & 0x1FFFFu);
    }
}

// ---------------------------------------------------------------------------
// Pull, feature-half pass: wave = 2 rows x 32 lanes. Lane covers 4 fp16
// features of the 128-half (8B gather/lane). cursor[row] = segment start.
// ---------------------------------------------------------------------------
__global__ __launch_bounds__(256) void pull_half_kernel(
    const int* __restrict__ counts, const int* __restrict__ cursor,
    const ull* __restrict__ scw, const __half* __restrict__ suph,
    const float* __restrict__ biash, float* __restrict__ outh, int M)
{
    const int wv  = blockIdx.x * 4 + (threadIdx.x >> 6);
    const int row = wv * 2 + ((threadIdx.x >> 5) & 1);
    if (row >= M) return;
    const int l = threadIdx.x & 31;

    const int cnt   = counts[row];
    const int start = cursor[row];

    float4 acc = *(const float4*)(biash + l * 4);

#define GATHER_FMA_H(pe)                                                      \
    {                                                                         \
        const int   c  = (int)(unsigned)(pe);                                 \
        const float wj = __uint_as_float((unsigned)((pe) >> 32));             \
        const uint2 v = *(const uint2*)(suph + (size_t)c * HALF_F + l * 4);   \
        const float2 f0 = __half22float2(*(const __half2*)&v.x);              \
        const float2 f1 = __half22float2(*(const __half2*)&v.y);              \
        acc.x = fmaf(wj, f0.x, acc.x); acc.y = fmaf(wj, f0.y, acc.y);         \
        acc.z = fmaf(wj, f1.x, acc.z); acc.w = fmaf(wj, f1.y, acc.w);         \
    }

    for (int j0 = 0; j0 < cnt; j0 += 32) {
        ull pr = 0ull;
        if (j0 + l < cnt)
            pr = __builtin_nontemporal_load(scw + start + j0 + l);
        const int m = min(32, cnt - j0);

        int j = 0;
        for (; j + 4 <= m; j += 4) {
            const ull p0 = __shfl(pr, j, 32),     p1 = __shfl(pr, j + 1, 32);
            const ull p2 = __shfl(pr, j + 2, 32), p3 = __shfl(pr, j + 3, 32);
            GATHER_FMA_H(p0); GATHER_FMA_H(p1);
            GATHER_FMA_H(p2); GATHER_FMA_H(p3);
        }
        for (; j < m; ++j) {
            const ull p = __shfl(pr, j, 32);
            GATHER_FMA_H(p);
        }
    }
#undef GATHER_FMA_H

    f32x4 o; o[0] = acc.x; o[1] = acc.y; o[2] = acc.z; o[3] = acc.w;
    __builtin_nontemporal_store(o, (f32x4*)(outh + (size_t)row * OUT_F + l * 4));
}

// --------------------------- fallback path ---------------------------
__global__ __launch_bounds__(256) void bias_init_kernel(
    float* __restrict__ out, const float* __restrict__ bias, int total4)
{
    const float4* b4 = (const float4*)bias;
    float4* o4 = (float4*)out;
    for (int i = blockIdx.x * blockDim.x + threadIdx.x; i < total4;
         i += gridDim.x * blockDim.x)
        o4[i] = b4[i & 63];
}

__global__ __launch_bounds__(256) void edge_scatter_kernel(
    const int* __restrict__ ei, const float* __restrict__ ew,
    const __half* __restrict__ supA, const __half* __restrict__ supB,
    float* __restrict__ out, int E)
{
    const int e = blockIdx.x * 4 + (threadIdx.x >> 6);
    if (e >= E) return;
    const int lane = threadIdx.x & 63;
    const int   row = ei[e];
    const int   col = ei[E + e];
    const float wgt = ew[e];
    const __half* src = (lane < 32) ? supA : supB;
    const int fl = (lane & 31) * 4;
    const uint2 v = *(const uint2*)(src + (size_t)col * HALF_F + fl);
    const float2 f0 = __half22float2(*(const __half2*)&v.x);
    const float2 f1 = __half22float2(*(const __half2*)&v.y);
    float* o = out + (size_t)row * OUT_F + (lane >> 5) * HALF_F + fl;
    unsafeAtomicAdd(o + 0, wgt * f0.x);
    unsafeAtomicAdd(o + 1, wgt * f0.y);
    unsafeAtomicAdd(o + 2, wgt * f1.x);
    unsafeAtomicAdd(o + 3, wgt * f1.y);
}

// ---------------------------------------------------------------------------
extern "C" void kernel_launch(void* const* d_in, const int* in_sizes, int n_in,
                              void* d_out, int out_size, void* d_ws, size_t ws_size,
                              hipStream_t stream)
{
    const float* x    = (const float*)d_in[0];
    const int*   ei   = (const int*)d_in[1];
    const float* ew   = (const float*)d_in[2];
    const float* w    = (const float*)d_in[3];
    const float* bias = (const float*)d_in[4];
    float* out = (float*)d_out;

    const int M = in_sizes[0] / IN_F;   // 100000
    const int E = in_sizes[2];          // 3,200,000
    const int nbins = (M + RPB - 1) >> RPB_SHIFT;        // 196
    const int T     = (E + TILE_E - 1) / TILE_E;         // 782

    // workspace: supA | supB | counts | btot | cursor | bstart | thist | scw | tscw | wt
    char* p = (char*)d_ws;
    const size_t suph_b   = (((size_t)M * HALF_F * sizeof(__half)) + 255) & ~255ull;
    const size_t counts_b = ((size_t)M * 4 + 255) & ~255ull;
    const size_t btot_b   = NBINS_MAX * 4;
    const size_t cursor_b = counts_b;
    const size_t bstart_b = NBINS_MAX * 4;
    const size_t thist_b  = (((size_t)T * NBINS_MAX * 4) + 255) & ~255ull;
    const size_t scw_b    = ((size_t)E * 8 + 255) & ~255ull;
    const size_t tscw_b   = scw_b;
    const size_t wt_b     = (size_t)IN_F * OUT_F * sizeof(short);
    const size_t need     = 2 * suph_b + counts_b + btot_b + cursor_b + bstart_b
                          + thist_b + scw_b + tscw_b + wt_b;

    __half* supA   = (__half*)p;               p += suph_b;
    __half* supB   = (__half*)p;               p += suph_b;
    int*    counts = (int*)p;                  p += counts_b;
    int*    btot   = (int*)p;                  p += btot_b;
    int*    cursor = (int*)p;                  p += cursor_b;
    int*    bstart = (int*)p;                  p += bstart_b;
    int*    thist  = (int*)p;                  p += thist_b;
    ull*    scw    = (ull*)p;                  p += scw_b;
    ull*    tscw   = (ull*)p;                  p += tscw_b;
    short*  wtb    = (short*)p;

    // 1) wt = bf16(w^T); supA/B = fp16(x @ W) via MFMA
    convert_wt_kernel<<<(IN_F * OUT_F) / 256, 256, 0, stream>>>(w, wtb);
    mfma_gemm_kernel<<<(M + 63) / 64, 256, 0, stream>>>(x, wtb, supA, supB, M);

    if (ws_size >= need) {
        // 2) CSR build: hist -> scans -> binned scatter -> in-bin sort
        a1a_hist_kernel<<<T, 256, 0, stream>>>(ei, thist, E);
        tile_scan_kernel<<<nbins, 256, 0, stream>>>(thist, btot, T);
        bin_scan_kernel<<<1, NBINS_MAX, 0, stream>>>(btot, bstart, nbins);
        a1b_scatter_kernel<<<T, 256, 0, stream>>>(ei, ew, bstart, thist, tscw, E);
        a2_sort_kernel<<<nbins, 256, 0, stream>>>(
            tscw, bstart, btot, counts, cursor, scw, M);
        // 3) pull, two feature-half passes (serialized -> halved hot footprint)
        const int pblocks = ((M + 1) / 2 + 3) / 4;
        pull_half_kernel<<<pblocks, 256, 0, stream>>>(
            counts, cursor, scw, supA, bias, out, M);
        pull_half_kernel<<<pblocks, 256, 0, stream>>>(
            counts, cursor, scw, supB, bias + HALF_F, out + HALF_F, M);
    } else {
        const int total4 = M * OUT_F / 4;
        bias_init_kernel<<<2048, 256, 0, stream>>>(out, bias, total4);
        edge_scatter_kernel<<<(E + 3) / 4, 256, 0, stream>>>(ei, ew, supA, supB, out, E);
    }
}

// Round 8
// 413.200 us; speedup vs baseline: 2.5864x; 1.1410x over previous
//
#include <hip/hip_runtime.h>
#include <hip/hip_fp16.h>

#define IN_F 256
#define OUT_F 256
#define HALF_F 128
#define RPB_SHIFT 9          // 512 rows per bin
#define RPB (1 << RPB_SHIFT)
#define NBINS_MAX 256
#define TILE_E 4096
#define XS_PAD 40            // LDS row stride in bf16 (80 B = 20 words; 16B-aligned, bank-spread)

using bf16x8 = __attribute__((ext_vector_type(8))) short;
using f32x4  = __attribute__((ext_vector_type(4))) float;
using ull    = unsigned long long;

__device__ inline short bf16rne(float f) {
    unsigned u = __float_as_uint(f);
    u = u + 0x7FFFu + ((u >> 16) & 1u);
    return (short)(u >> 16);
}
__device__ inline unsigned pack_half2(float a, float b) {
    __half2 h = __floats2half2_rn(a, b);
    return *reinterpret_cast<unsigned*>(&h);
}

// ---------------------------------------------------------------------------
// wt[n][k] = bf16(w[k][n])
// ---------------------------------------------------------------------------
__global__ __launch_bounds__(256) void convert_wt_kernel(
    const float* __restrict__ w, short* __restrict__ wt)
{
    const int idx = blockIdx.x * blockDim.x + threadIdx.x;
    const int c = idx >> 8, k = idx & 255;
    wt[(size_t)c * IN_F + k] = bf16rne(w[(size_t)k * OUT_F + c]);
}

// ---------------------------------------------------------------------------
// MFMA GEMM, LDS-staged + double-buffered.
// Block: 256 thr / 4 waves, tile 64 rows x 256 cols; wave w owns cols w*64..+63.
// Per k-step (32 k): stage x[64][32] as bf16 in LDS (each thread 32B load ->
// convert -> 1x ds_write_b128); waves ds_read_b128 fragments; 16 MFMA.
// Double-buffered: k+1 global load issued before k's MFMAs; 1 sync/step.
// ---------------------------------------------------------------------------
__global__ __launch_bounds__(256) void mfma_gemm_kernel(
    const float* __restrict__ x, const short* __restrict__ wt,
    __half* __restrict__ supA, __half* __restrict__ supB, int M)
{
    __shared__ short xs[2][64][XS_PAD];

    const int t    = threadIdx.x;
    const int lane = t & 63;
    const int wid  = t >> 6;
    const int l15  = lane & 15;
    const int l4   = lane >> 4;
    const int rowbase = blockIdx.x * 64;
    const int cbase   = wid * 64;

    // staging mapping: thread t -> row t>>2, k-offset (t&3)*8
    const int srow = t >> 2;
    const int sks  = (t & 3) * 8;
    int grow = rowbase + srow; if (grow > M - 1) grow = M - 1;
    const float* xsrc = x + (size_t)grow * IN_F + sks;

    f32x4 acc[4][4];
#pragma unroll
    for (int rt = 0; rt < 4; ++rt)
#pragma unroll
        for (int ct = 0; ct < 4; ++ct)
            acc[rt][ct] = (f32x4){0.f, 0.f, 0.f, 0.f};

    const short* wp[4];
#pragma unroll
    for (int ct = 0; ct < 4; ++ct)
        wp[ct] = wt + (size_t)(cbase + ct * 16 + l15) * IN_F + l4 * 8;

    // prologue: stage k0 = 0
    {
        const float4 f0 = *(const float4*)(xsrc + 0);
        const float4 f1 = *(const float4*)(xsrc + 4);
        bf16x8 v;
        v[0] = bf16rne(f0.x); v[1] = bf16rne(f0.y);
        v[2] = bf16rne(f0.z); v[3] = bf16rne(f0.w);
        v[4] = bf16rne(f1.x); v[5] = bf16rne(f1.y);
        v[6] = bf16rne(f1.z); v[7] = bf16rne(f1.w);
        *(bf16x8*)&xs[0][srow][sks] = v;
    }
    __syncthreads();

#pragma unroll
    for (int k0 = 0; k0 < 8; ++k0) {
        const int cur = k0 & 1;

        // issue next k-tile's global loads FIRST (overlap with ds_read+MFMA)
        float4 nf0, nf1;
        if (k0 < 7) {
            nf0 = *(const float4*)(xsrc + (k0 + 1) * 32);
            nf1 = *(const float4*)(xsrc + (k0 + 1) * 32 + 4);
        }

        bf16x8 b[4];
#pragma unroll
        for (int ct = 0; ct < 4; ++ct)
            b[ct] = *(const bf16x8*)(wp[ct] + k0 * 32);

        bf16x8 a[4];
#pragma unroll
        for (int rt = 0; rt < 4; ++rt)
            a[rt] = *(const bf16x8*)&xs[cur][rt * 16 + l15][l4 * 8];

#pragma unroll
        for (int rt = 0; rt < 4; ++rt)
#pragma unroll
            for (int ct = 0; ct < 4; ++ct)
                acc[rt][ct] = __builtin_amdgcn_mfma_f32_16x16x32_bf16(
                    b[ct], a[rt], acc[rt][ct], 0, 0, 0);

        if (k0 < 7) {
            bf16x8 v;
            v[0] = bf16rne(nf0.x); v[1] = bf16rne(nf0.y);
            v[2] = bf16rne(nf0.z); v[3] = bf16rne(nf0.w);
            v[4] = bf16rne(nf1.x); v[5] = bf16rne(nf1.y);
            v[6] = bf16rne(nf1.z); v[7] = bf16rne(nf1.w);
            *(bf16x8*)&xs[cur ^ 1][srow][sks] = v;
        }
        __syncthreads();
    }

    __half* dst = (wid < 2) ? supA : supB;
    const int fbase = (wid & 1) * 64;
#pragma unroll
    for (int rt = 0; rt < 4; ++rt) {
        const int r = rowbase + rt * 16 + l15;
        if (r >= M) continue;
#pragma unroll
        for (int ct = 0; ct < 4; ++ct) {
            uint2 pk;
            pk.x = pack_half2(acc[rt][ct][0], acc[rt][ct][1]);
            pk.y = pack_half2(acc[rt][ct][2], acc[rt][ct][3]);
            *(uint2*)(dst + (size_t)r * HALF_F + fbase + ct * 16 + l4 * 4) = pk;
        }
    }
}

// ---------------------------------------------------------------------------
// a1a: per-tile bin histogram -> thist[t][b]   (LDS atomics only)
// ---------------------------------------------------------------------------
__global__ __launch_bounds__(256) void a1a_hist_kernel(
    const int* __restrict__ ei, int* __restrict__ thist, int E)
{
    __shared__ int hist[NBINS_MAX];
    const int tid = threadIdx.x;
    hist[tid] = 0;
    __syncthreads();
    const int base = blockIdx.x * TILE_E;
#pragma unroll
    for (int i = 0; i < TILE_E / 256; ++i) {
        const int e = base + i * 256 + tid;
        if (e < E)
            atomicAdd(&hist[__builtin_nontemporal_load(ei + e) >> RPB_SHIFT], 1);
    }
    __syncthreads();
    thist[(size_t)blockIdx.x * NBINS_MAX + tid] = hist[tid];
}

// per-bin exclusive scan over tiles, in place; also emits btot[b]
__global__ __launch_bounds__(256) void tile_scan_kernel(
    int* __restrict__ thist, int* __restrict__ btot, int T)
{
    const int b   = blockIdx.x;
    const int tid = threadIdx.x;
    __shared__ int s[256];
    int carry = 0;
    for (int c0 = 0; c0 < T; c0 += 256) {
        const int t = c0 + tid;
        const int v = (t < T) ? thist[(size_t)t * NBINS_MAX + b] : 0;
        s[tid] = v;
        __syncthreads();
        for (int d = 1; d < 256; d <<= 1) {
            const int u = (tid >= d) ? s[tid - d] : 0;
            __syncthreads();
            s[tid] += u;
            __syncthreads();
        }
        const int total = s[255];
        if (t < T) thist[(size_t)t * NBINS_MAX + b] = carry + s[tid] - v;
        carry += total;
        __syncthreads();
    }
    if (tid == 0) btot[b] = carry;
}

// exclusive scan of bin totals (1 block)
__global__ __launch_bounds__(NBINS_MAX) void bin_scan_kernel(
    const int* __restrict__ btot, int* __restrict__ bstart, int nbins)
{
    __shared__ int s[NBINS_MAX];
    const int tid = threadIdx.x;
    const int v = (tid < nbins) ? btot[tid] : 0;
    s[tid] = v;
    __syncthreads();
    for (int d = 1; d < NBINS_MAX; d <<= 1) {
        const int u = (tid >= d) ? s[tid - d] : 0;
        __syncthreads();
        s[tid] += u;
        __syncthreads();
    }
    bstart[tid] = s[tid] - v;
}

// ---------------------------------------------------------------------------
// a1b: deterministic binned scatter. pos = bstart[b] + thist[t][b] + LDS-rank.
// Entry = (w:32 | col:17 | rowLo:9)
// ---------------------------------------------------------------------------
__global__ __launch_bounds__(256) void a1b_scatter_kernel(
    const int* __restrict__ ei, const float* __restrict__ ew,
    const int* __restrict__ bstart, const int* __restrict__ thist,
    ull* __restrict__ tscw, int E)
{
    __shared__ int hist[NBINS_MAX];
    __shared__ int rbase[NBINS_MAX];
    const int tid = threadIdx.x;
    hist[tid]  = 0;
    rbase[tid] = bstart[tid] + thist[(size_t)blockIdx.x * NBINS_MAX + tid];
    __syncthreads();
    const int base = blockIdx.x * TILE_E;
#pragma unroll
    for (int i = 0; i < TILE_E / 256; ++i) {
        const int e = base + i * 256 + tid;
        if (e < E) {
            const int      row = __builtin_nontemporal_load(ei + e);
            const int      col = __builtin_nontemporal_load(ei + E + e);
            const unsigned wb  = __builtin_nontemporal_load((const unsigned*)ew + e);
            const int b   = row >> RPB_SHIFT;
            const int rnk = atomicAdd(&hist[b], 1);
            tscw[rbase[b] + rnk] = ((ull)wb << 32) |
                                   ((unsigned)col << RPB_SHIFT) |
                                   (unsigned)(row & (RPB - 1));
        }
    }
}

// ---------------------------------------------------------------------------
// a2: in-bin LDS counting sort. One block per bin. Emits row-sorted scw,
// plus counts[row] and cursor[row] (= segment start). No global atomics.
// ---------------------------------------------------------------------------
__global__ __launch_bounds__(256) void a2_sort_kernel(
    const ull* __restrict__ tscw, const int* __restrict__ bstart,
    const int* __restrict__ btot, int* __restrict__ counts,
    int* __restrict__ cursor, ull* __restrict__ scw, int M)
{
    const int b   = blockIdx.x;
    const int tid = threadIdx.x;
    const int n   = btot[b];
    const int s0  = bstart[b];

    __shared__ int hist[RPB];
    __shared__ int cur[RPB];
    __shared__ int s[256];

    hist[tid] = 0; hist[tid + 256] = 0;
    __syncthreads();

    for (int i = tid; i < n; i += 256)
        atomicAdd(&hist[(int)(__builtin_nontemporal_load(tscw + s0 + i) & (RPB - 1))], 1);
    __syncthreads();

    const int h0 = hist[2 * tid], h1 = hist[2 * tid + 1];
    const int own = h0 + h1;
    s[tid] = own;
    __syncthreads();
    for (int d = 1; d < 256; d <<= 1) {
        const int u = (tid >= d) ? s[tid - d] : 0;
        __syncthreads();
        s[tid] += u;
        __syncthreads();
    }
    const int excl = s[tid] - own;

    const int r0 = (b << RPB_SHIFT) + 2 * tid, r1 = r0 + 1;
    cur[2 * tid]     = s0 + excl;
    cur[2 * tid + 1] = s0 + excl + h0;
    if (r0 < M) { counts[r0] = h0; cursor[r0] = s0 + excl; }
    if (r1 < M) { counts[r1] = h1; cursor[r1] = s0 + excl + h0; }
    __syncthreads();

    for (int i = tid; i < n; i += 256) {
        const ull en = __builtin_nontemporal_load(tscw + s0 + i);
        const int pos = atomicAdd(&cur[(int)(en & (RPB - 1))], 1);
        scw[pos] = (en & 0xFFFFFFFF00000000ull) |
                   (unsigned)((en >> RPB_SHIFT) & 0x1FFFFu);
    }
}

// ---------------------------------------------------------------------------
// Pull, feature-half pass: wave = 2 rows x 32 lanes.
// ---------------------------------------------------------------------------
__global__ __launch_bounds__(256) void pull_half_kernel(
    const int* __restrict__ counts, const int* __restrict__ cursor,
    const ull* __restrict__ scw, const __half* __restrict__ suph,
    const float* __restrict__ biash, float* __restrict__ outh, int M)
{
    const int wv  = blockIdx.x * 4 + (threadIdx.x >> 6);
    const int row = wv * 2 + ((threadIdx.x >> 5) & 1);
    if (row >= M) return;
    const int l = threadIdx.x & 31;

    const int cnt   = counts[row];
    const int start = cursor[row];

    float4 acc = *(const float4*)(biash + l * 4);

#define GATHER_FMA_H(pe)                                                      \
    {                                                                         \
        const int   c  = (int)(unsigned)(pe);                                 \
        const float wj = __uint_as_float((unsigned)((pe) >> 32));             \
        const uint2 v = *(const uint2*)(suph + (size_t)c * HALF_F + l * 4);   \
        const float2 f0 = __half22float2(*(const __half2*)&v.x);              \
        const float2 f1 = __half22float2(*(const __half2*)&v.y);              \
        acc.x = fmaf(wj, f0.x, acc.x); acc.y = fmaf(wj, f0.y, acc.y);         \
        acc.z = fmaf(wj, f1.x, acc.z); acc.w = fmaf(wj, f1.y, acc.w);         \
    }

    for (int j0 = 0; j0 < cnt; j0 += 32) {
        ull pr = 0ull;
        if (j0 + l < cnt)
            pr = __builtin_nontemporal_load(scw + start + j0 + l);
        const int m = min(32, cnt - j0);

        int j = 0;
        for (; j + 4 <= m; j += 4) {
            const ull p0 = __shfl(pr, j, 32),     p1 = __shfl(pr, j + 1, 32);
            const ull p2 = __shfl(pr, j + 2, 32), p3 = __shfl(pr, j + 3, 32);
            GATHER_FMA_H(p0); GATHER_FMA_H(p1);
            GATHER_FMA_H(p2); GATHER_FMA_H(p3);
        }
        for (; j < m; ++j) {
            const ull p = __shfl(pr, j, 32);
            GATHER_FMA_H(p);
        }
    }
#undef GATHER_FMA_H

    f32x4 o; o[0] = acc.x; o[1] = acc.y; o[2] = acc.z; o[3] = acc.w;
    __builtin_nontemporal_store(o, (f32x4*)(outh + (size_t)row * OUT_F + l * 4));
}

// --------------------------- fallback path ---------------------------
__global__ __launch_bounds__(256) void bias_init_kernel(
    float* __restrict__ out, const float* __restrict__ bias, int total4)
{
    const float4* b4 = (const float4*)bias;
    float4* o4 = (float4*)out;
    for (int i = blockIdx.x * blockDim.x + threadIdx.x; i < total4;
         i += gridDim.x * blockDim.x)
        o4[i] = b4[i & 63];
}

__global__ __launch_bounds__(256) void edge_scatter_kernel(
    const int* __restrict__ ei, const float* __restrict__ ew,
    const __half* __restrict__ supA, const __half* __restrict__ supB,
    float* __restrict__ out, int E)
{
    const int e = blockIdx.x * 4 + (threadIdx.x >> 6);
    if (e >= E) return;
    const int lane = threadIdx.x & 63;
    const int   row = ei[e];
    const int   col = ei[E + e];
    const float wgt = ew[e];
    const __half* src = (lane < 32) ? supA : supB;
    const int fl = (lane & 31) * 4;
    const uint2 v = *(const uint2*)(src + (size_t)col * HALF_F + fl);
    const float2 f0 = __half22float2(*(const __half2*)&v.x);
    const float2 f1 = __half22float2(*(const __half2*)&v.y);
    float* o = out + (size_t)row * OUT_F + (lane >> 5) * HALF_F + fl;
    unsafeAtomicAdd(o + 0, wgt * f0.x);
    unsafeAtomicAdd(o + 1, wgt * f0.y);
    unsafeAtomicAdd(o + 2, wgt * f1.x);
    unsafeAtomicAdd(o + 3, wgt * f1.y);
}

// ---------------------------------------------------------------------------
extern "C" void kernel_launch(void* const* d_in, const int* in_sizes, int n_in,
                              void* d_out, int out_size, void* d_ws, size_t ws_size,
                              hipStream_t stream)
{
    const float* x    = (const float*)d_in[0];
    const int*   ei   = (const int*)d_in[1];
    const float* ew   = (const float*)d_in[2];
    const float* w    = (const float*)d_in[3];
    const float* bias = (const float*)d_in[4];
    float* out = (float*)d_out;

    const int M = in_sizes[0] / IN_F;   // 100000
    const int E = in_sizes[2];          // 3,200,000
    const int nbins = (M + RPB - 1) >> RPB_SHIFT;        // 196
    const int T     = (E + TILE_E - 1) / TILE_E;         // 782

    // workspace: supA | supB | counts | btot | cursor | bstart | thist | scw | tscw | wt
    char* p = (char*)d_ws;
    const size_t suph_b   = (((size_t)M * HALF_F * sizeof(__half)) + 255) & ~255ull;
    const size_t counts_b = ((size_t)M * 4 + 255) & ~255ull;
    const size_t btot_b   = NBINS_MAX * 4;
    const size_t cursor_b = counts_b;
    const size_t bstart_b = NBINS_MAX * 4;
    const size_t thist_b  = (((size_t)T * NBINS_MAX * 4) + 255) & ~255ull;
    const size_t scw_b    = ((size_t)E * 8 + 255) & ~255ull;
    const size_t tscw_b   = scw_b;
    const size_t wt_b     = (size_t)IN_F * OUT_F * sizeof(short);
    const size_t need     = 2 * suph_b + counts_b + btot_b + cursor_b + bstart_b
                          + thist_b + scw_b + tscw_b + wt_b;

    __half* supA   = (__half*)p;               p += suph_b;
    __half* supB   = (__half*)p;               p += suph_b;
    int*    counts = (int*)p;                  p += counts_b;
    int*    btot   = (int*)p;                  p += btot_b;
    int*    cursor = (int*)p;                  p += cursor_b;
    int*    bstart = (int*)p;                  p += bstart_b;
    int*    thist  = (int*)p;                  p += thist_b;
    ull*    scw    = (ull*)p;                  p += scw_b;
    ull*    tscw   = (ull*)p;                  p += tscw_b;
    short*  wtb    = (short*)p;

    // 1) wt = bf16(w^T); supA/B = fp16(x @ W) via LDS-staged MFMA
    convert_wt_kernel<<<(IN_F * OUT_F) / 256, 256, 0, stream>>>(w, wtb);
    mfma_gemm_kernel<<<(M + 63) / 64, 256, 0, stream>>>(x, wtb, supA, supB, M);

    if (ws_size >= need) {
        // 2) CSR build: hist -> scans -> binned scatter -> in-bin sort
        a1a_hist_kernel<<<T, 256, 0, stream>>>(ei, thist, E);
        tile_scan_kernel<<<nbins, 256, 0, stream>>>(thist, btot, T);
        bin_scan_kernel<<<1, NBINS_MAX, 0, stream>>>(btot, bstart, nbins);
        a1b_scatter_kernel<<<T, 256, 0, stream>>>(ei, ew, bstart, thist, tscw, E);
        a2_sort_kernel<<<nbins, 256, 0, stream>>>(
            tscw, bstart, btot, counts, cursor, scw, M);
        // 3) pull, two feature-half passes (halved hot footprint per pass)
        const int pblocks = ((M + 1) / 2 + 3) / 4;
        pull_half_kernel<<<pblocks, 256, 0, stream>>>(
            counts, cursor, scw, supA, bias, out, M);
        pull_half_kernel<<<pblocks, 256, 0, stream>>>(
            counts, cursor, scw, supB, bias + HALF_F, out + HALF_F, M);
    } else {
        const int total4 = M * OUT_F / 4;
        bias_init_kernel<<<2048, 256, 0, stream>>>(out, bias, total4);
        edge_scatter_kernel<<<(E + 3) / 4, 256, 0, stream>>>(ei, ew, supA, supB, out, E);
    }
}